// Round 9
// baseline (308.421 us; speedup 1.0000x reference)
//
#include <hip/hip_runtime.h>
#include <hip/hip_cooperative_groups.h>

namespace cg = cooperative_groups;

// (B,E,K,C) = (64,32,128,512), fp32.
#define BB 64
#define EE 32
#define KK 128
#define CC 512
#define V0EPS 1e-7f

#define LTR 132   // [32][132] padded stride
#define PTS 132   // scan: P^T / RhsT / WrT row stride
#define LKM 36    // scan: k-major row stride (G/Y/Egg)
#define L36 36    // scan: S/D row stride
#define LWT 176   // postB: Wt^T row stride
// segment-padded K-vector layout: element i lives at (i/16)*20 + (i%16)
#define SEG(i) ((((i) >> 4) * 20) + ((i) & 15))

// scan sScal slots (order matters: read as two float4s in PH5)
#define SC_S2  0
#define SC_SIG 1
#define SC_KL  2
#define SC_B1  3
#define SC_B2  4
#define SC_R11 5
#define SC_R12 6
#define SC_R22 7

__device__ __forceinline__ float wsum64(float v) {
#pragma unroll
  for (int m = 32; m >= 1; m >>= 1) v += __shfl_xor(v, m, 64);
  return v;
}

__device__ __forceinline__ float wsum32(float v) {  // reduce within aligned 32-lane half
#pragma unroll
  for (int m = 16; m >= 1; m >>= 1) v += __shfl_xor(v, m, 64);
  return v;
}

__device__ __forceinline__ float dot4(const float4 a, const float4 b) {
  return a.x * b.x + a.y * b.y + a.z * b.z + a.w * b.w;
}

// ---------------- Kernel 1: A0 = M0 M0^T + I (512 WGs: k x l-quarter) ----------------
__global__ __launch_bounds__(256) void a0_kernel(const float* __restrict__ M0,
                                                 float* __restrict__ wsA0) {
  __shared__ __align__(16) float sRow[CC];
  const int k = blockIdx.x >> 2, quarter = blockIdx.x & 3;
  for (int c = threadIdx.x; c < CC; c += 256) sRow[c] = M0[k * CC + c];
  __syncthreads();
  const int wv = threadIdx.x >> 6, ln = threadIdx.x & 63;
  const float4* zr = (const float4*)(sRow + 8 * ln);
  const float4 z0 = zr[0], z1 = zr[1];
  for (int li = 0; li < 8; ++li) {
    const int l = quarter * 32 + wv * 8 + li;
    const float4* rp = (const float4*)(M0 + l * CC + 8 * ln);
    const float4 a = rp[0], b = rp[1];
    float s = dot4(a, z0) + dot4(b, z1);
    s = wsum64(s);
    if (ln == 0) wsA0[k * KK + l] = s + (l == k ? 1.0f : 0.0f);
  }
}

// ------- Kernel 2: block 0 -> inv(A0) via 4-pivot GJ ; blocks 1..256 -> P/S partials -------
__global__ __launch_bounds__(1024) void psinv_kernel(const float* __restrict__ x,
                                                     const float* __restrict__ M0,
                                                     float* __restrict__ wsP,
                                                     float* __restrict__ wsSp,
                                                     const float* __restrict__ A0g,
                                                     float* __restrict__ Ainv0) {
  __shared__ __align__(16) float zAll[32][520];
  __shared__ __align__(16) float Mch[2][16][520];
  __shared__ __align__(16) float sFb[2][4][128];   // [buf][col j+i][row]
  __shared__ __align__(16) float sPv[2][4][256];   // [buf][row j+i][A-part 128 | I-part 128]
  const int tid = threadIdx.x;

  if (blockIdx.x > 0) {
    // ================= ps body: P rows kq*32..kq*32+31 ; S partial over c-quarter =================
    const int b = (blockIdx.x - 1) >> 2, kq = (blockIdx.x - 1) & 3;
    {
      const float4* x4 = (const float4*)(x + (size_t)b * EE * CC);
#pragma unroll
      for (int i = 0; i < 4; i++) {
        const int F = tid + 1024 * i, e = F >> 7, c4 = F & 127;
        ((float4*)zAll[e])[c4] = x4[F];
      }
    }
    const float4* M4 = (const float4*)M0;
    const int srow = tid >> 7, sc4 = tid & 127;
    const int kbase = kq * 32;
    float4 st0 = M4[(kbase + srow) * 128 + sc4];
    float4 st1 = M4[(kbase + 8 + srow) * 128 + sc4];
    int buf = 0;
    const int p = tid & 7;           // 8 threads per dot
    const int ep = (tid >> 3) & 15;  // episodes 2*ep, 2*ep+1  (0..31)
    const int kp = tid >> 7;         // k rows kp, kp+8
#pragma unroll 1
    for (int kc = 0; kc < 2; ++kc) {
      ((float4*)Mch[buf][srow])[sc4] = st0;
      ((float4*)Mch[buf][8 + srow])[sc4] = st1;
      __syncthreads();
      if (kc == 0) {
        st0 = M4[(kbase + 16 + srow) * 128 + sc4];
        st1 = M4[(kbase + 24 + srow) * 128 + sc4];
      }
      float s00 = 0, s01 = 0, s10 = 0, s11 = 0;
      const float* m0 = Mch[buf][kp];
      const float* m1 = Mch[buf][kp + 8];
      const float* z0 = zAll[2 * ep];
      const float* z1 = zAll[2 * ep + 1];
#pragma unroll
      for (int u = 0; u < 16; u++) {
        const int c = 4 * p + 32 * u;
        const float4 a0 = *(const float4*)(m0 + c);
        const float4 a1 = *(const float4*)(m1 + c);
        const float4 b0 = *(const float4*)(z0 + c);
        const float4 b1 = *(const float4*)(z1 + c);
        s00 += dot4(a0, b0); s01 += dot4(a0, b1);
        s10 += dot4(a1, b0); s11 += dot4(a1, b1);
      }
#pragma unroll
      for (int m = 1; m <= 4; m <<= 1) {
        s00 += __shfl_xor(s00, m, 64); s01 += __shfl_xor(s01, m, 64);
        s10 += __shfl_xor(s10, m, 64); s11 += __shfl_xor(s11, m, 64);
      }
      if (p == 0) {
        float* Pb = wsP + (size_t)b * KK * EE;
        Pb[(kbase + kc * 16 + kp) * EE + 2 * ep] = s00;
        Pb[(kbase + kc * 16 + kp) * EE + 2 * ep + 1] = s01;
        Pb[(kbase + kc * 16 + kp + 8) * EE + 2 * ep] = s10;
        Pb[(kbase + kc * 16 + kp + 8) * EE + 2 * ep + 1] = s11;
      }
      buf ^= 1;
    }
    // S partial = Z[:, cq] Z[:, cq]^T
    {
      const int e = tid >> 5, f = tid & 31;
      const float4* ze = ((const float4*)zAll[e]) + 32 * kq;
      const float4* zf = ((const float4*)zAll[f]) + 32 * kq;
      float a0 = 0, a1 = 0, a2 = 0, a3 = 0;
#pragma unroll 4
      for (int u = 0; u < 32; u++) {
        const float4 A = ze[u], Bq = zf[u];
        a0 += A.x * Bq.x; a1 += A.y * Bq.y; a2 += A.z * Bq.z; a3 += A.w * Bq.w;
      }
      wsSp[((size_t)b * 4 + kq) * 1024 + e * EE + f] = (a0 + a1) + (a2 + a3);
    }
  } else {
    // ======== inv0 body (block 0): 4-pivot register GJ, 32 super-iterations ========
    const int r = tid >> 3, q = tid & 7;
    float wreg[16], vreg[16];
    {
      const float4* a4 = (const float4*)(A0g + r * KK + 16 * q);
#pragma unroll
      for (int u = 0; u < 4; u++) {
        const float4 t4 = a4[u];
        wreg[4 * u] = t4.x; wreg[4 * u + 1] = t4.y; wreg[4 * u + 2] = t4.z; wreg[4 * u + 3] = t4.w;
      }
#pragma unroll
      for (int c = 0; c < 16; c++) vreg[c] = (16 * q + c == r) ? 1.0f : 0.0f;
    }
    // prologue: stage cols 0..3 and rows 0..3
    if (q == 0) {
      sFb[0][0][r] = wreg[0]; sFb[0][1][r] = wreg[1];
      sFb[0][2][r] = wreg[2]; sFb[0][3][r] = wreg[3];
    }
    if (r < 4) {
#pragma unroll
      for (int c = 0; c < 16; c++) {
        sPv[0][r][16 * q + c] = wreg[c];
        sPv[0][r][128 + 16 * q + c] = vreg[c];
      }
    }
    __syncthreads();
#pragma unroll 1
    for (int jj = 0; jj < 32; ++jj) {
      const int j = 4 * jj, db = jj & 1, dn = db ^ 1;
      const float* c0 = sFb[db][0];
      const float* c1 = sFb[db][1];
      const float* c2 = sFb[db][2];
      const float* c3 = sFb[db][3];
      const float* r0 = sPv[db][0];
      const float* r1 = sPv[db][1];
      const float* r2 = sPv[db][2];
      const float* r3 = sPv[db][3];
      const float p00 = c0[j],     p01 = c1[j],     p02 = c2[j],     p03 = c3[j];
      const float p10 = c0[j + 1], p11 = c1[j + 1], p12 = c2[j + 1], p13 = c3[j + 1];
      const float p20 = c0[j + 2], p21 = c1[j + 2], p22 = c2[j + 2], p23 = c3[j + 2];
      const float p30 = c0[j + 3], p31 = c1[j + 3], p32 = c2[j + 3], p33 = c3[j + 3];
      const float rp00 = 1.0f / p00;
      const float g10 = p10 * rp00;
      const float q11 = p11 - g10 * p01, q12 = p12 - g10 * p02, q13 = p13 - g10 * p03;
      const float rq11 = 1.0f / q11;
      const float g20 = p20 * rp00;
      const float g21 = (p21 - g20 * p01) * rq11;
      const float q22 = p22 - g20 * p02 - g21 * q12;
      const float q23 = p23 - g20 * p03 - g21 * q13;
      const float rq22 = 1.0f / q22;
      const float g30 = p30 * rp00;
      const float g31 = (p31 - g30 * p01) * rq11;
      const float g32 = (p32 - g30 * p02 - g31 * q12) * rq22;
      const float q33 = p33 - g30 * p03 - g31 * q13 - g32 * q23;
      const float rq33 = 1.0f / q33;
      const float f0 = (r == j) ? 0.0f : c0[r] * rp00;
      const float f1 = (r == j + 1) ? 0.0f : (c1[r] - f0 * p01) * rq11;
      const float f2 = (r == j + 2) ? 0.0f : (c2[r] - f0 * p02 - f1 * q12) * rq22;
      const float f3 = (r == j + 3) ? 0.0f : (c3[r] - f0 * p03 - f1 * q13 - f2 * q23) * rq33;
      const float cc3 = f3;
      const float cc2 = f2 - cc3 * g32;
      const float cc1 = f1 - cc2 * g21 - cc3 * g31;
      const float cc0 = f0 - cc1 * g10 - cc2 * g20 - cc3 * g30;
      if (16 * q + 15 >= j) {  // A-part: only cols >= j are touched
        const float4* w0 = (const float4*)(r0 + 16 * q);
        const float4* w1 = (const float4*)(r1 + 16 * q);
        const float4* w2 = (const float4*)(r2 + 16 * q);
        const float4* w3 = (const float4*)(r3 + 16 * q);
#pragma unroll
        for (int u = 0; u < 4; u++) {
          const float4 a0 = w0[u], a1 = w1[u], a2 = w2[u], a3 = w3[u];
          wreg[4 * u]     -= cc0 * a0.x + cc1 * a1.x + cc2 * a2.x + cc3 * a3.x;
          wreg[4 * u + 1] -= cc0 * a0.y + cc1 * a1.y + cc2 * a2.y + cc3 * a3.y;
          wreg[4 * u + 2] -= cc0 * a0.z + cc1 * a1.z + cc2 * a2.z + cc3 * a3.z;
          wreg[4 * u + 3] -= cc0 * a0.w + cc1 * a1.w + cc2 * a2.w + cc3 * a3.w;
        }
      }
      if (16 * q <= j + 3) {  // I-part: staged rows' I-support is cols <= j+3
        const float4* v0 = (const float4*)(r0 + 128 + 16 * q);
        const float4* v1 = (const float4*)(r1 + 128 + 16 * q);
        const float4* v2 = (const float4*)(r2 + 128 + 16 * q);
        const float4* v3 = (const float4*)(r3 + 128 + 16 * q);
#pragma unroll
        for (int u = 0; u < 4; u++) {
          const float4 a0 = v0[u], a1 = v1[u], a2 = v2[u], a3 = v3[u];
          vreg[4 * u]     -= cc0 * a0.x + cc1 * a1.x + cc2 * a2.x + cc3 * a3.x;
          vreg[4 * u + 1] -= cc0 * a0.y + cc1 * a1.y + cc2 * a2.y + cc3 * a3.y;
          vreg[4 * u + 2] -= cc0 * a0.z + cc1 * a1.z + cc2 * a2.z + cc3 * a3.z;
          vreg[4 * u + 3] -= cc0 * a0.w + cc1 * a1.w + cc2 * a2.w + cc3 * a3.w;
        }
      }
      if (jj + 1 < 32) {  // stage cols/rows j+4..j+7 (post-update values)
#pragma unroll
        for (int i = 0; i < 4; ++i) {
          const int j2 = j + 4 + i;
          float wv_ = 0.0f;
#pragma unroll
          for (int c = 0; c < 16; c++) if (c == (j2 & 15)) wv_ = wreg[c];
          if (q == (j2 >> 4)) sFb[dn][i][r] = wv_;
          if (r == j2) {
#pragma unroll
            for (int c = 0; c < 16; c++) {
              sPv[dn][i][16 * q + c] = wreg[c];
              sPv[dn][i][128 + 16 * q + c] = vreg[c];
            }
          }
        }
      }
      __syncthreads();
    }
    {
      float dval = 0.0f;
#pragma unroll
      for (int c = 0; c < 16; c++) if (c == (r & 15)) dval = wreg[c];
      if (q == (r >> 4)) sFb[0][0][r] = dval;
    }
    __syncthreads();
    {
      const float sc = 1.0f / sFb[0][0][r];
      float4* o4 = (float4*)(Ainv0 + r * KK + 16 * q);
#pragma unroll
      for (int u = 0; u < 4; u++) {
        float4 o;
        o.x = vreg[4 * u] * sc; o.y = vreg[4 * u + 1] * sc;
        o.z = vreg[4 * u + 2] * sc; o.w = vreg[4 * u + 3] * sc;
        o4[u] = o;
      }
    }
  }
}

// ---------- Kernel 3 (cooperative): scan+postA (WGs 0..63) -> grid sync -> postB+final (all 256) ----------
// Phase C is the byte-identical R8 scan body (LDS renamed into one aliased SM[]);
// Phase D is the byte-identical R8 postB quarter; WG 0 appends the final reduction.
__global__ __launch_bounds__(512) void scanpost_kernel(
    const float* __restrict__ Pg, const float* __restrict__ Sg,
    const float* __restrict__ scaleP, const float* __restrict__ Ainv0,
    float* __restrict__ wsKL, float* __restrict__ wsKLr, float* __restrict__ wsWt,
    const float* __restrict__ x, const float* __restrict__ M0,
    const float* __restrict__ znoise, const float* __restrict__ lwsP,
    float* __restrict__ out) {
  __shared__ __align__(16) float SM[33936];  // 135.7 KB, phase-aliased
  const int tid = threadIdx.x;

  if (blockIdx.x < 64) {
    // ================= Phase C: scan + fused postA (identical to R8) =================
    float* sPT   = SM;           // [32][132]
    float* sGT   = SM + 4224;    // [32][132]
    float* sEggT = SM + 8448;    // [32][132]
    float* uni2  = SM + 12672;   // [32][132]  scan: Y^T | postA: R1T+GamT
    float* uni3  = SM + 16896;   // [128][36]  scan: G   | postA: WrT
    float* uni1  = SM + 21504;   // [128][36]  scan: Y   | postA: RhsT
    float* sEk   = SM + 26112;   // [128][36]
    float* sS    = SM + 30720;   // [32][36]
    float* sD    = SM + 31872;   // [32][36]
    float* sW    = SM + 33024;   // 160
    float* sWU   = SM + 33184;
    float* sPu   = SM + 33344;
    float* sPm   = SM + 33504;
    float* sQ    = SM + 33664;
    float* sDz   = SM + 33824;   // 32
    float* sDgw  = SM + 33856;   // 32
    float* sQt   = SM + 33888;   // 32
    float* sScal = SM + 33920;   // 16
    float* sYT = uni2;
    float* sGk = uni3;
    float* sYk = uni1;

    const int wv = tid >> 6, ln = tid & 63;
    const int mr = tid >> 2, mq = tid & 3;  // matvec: row mr, col-quarter mq
    const int b = blockIdx.x;

    float areg[32];
    {
      const float4* a4 = (const float4*)(Ainv0 + mr * KK + 32 * mq);
#pragma unroll
      for (int u = 0; u < 8; u++) {
        const float4 t4 = a4[u];
        areg[4 * u] = t4.x; areg[4 * u + 1] = t4.y; areg[4 * u + 2] = t4.z; areg[4 * u + 3] = t4.w;
      }
    }
    {
      const float* Pb = Pg + (size_t)b * KK * EE;
#pragma unroll
      for (int i = 0; i < 8; i++) {
        const int idx = tid + 512 * i;                  // idx = k*32 + e
        sPT[(idx & 31) * PTS + (idx >> 5)] = Pb[idx];   // transpose into [e][k]
      }
      const float* Sb = Sg + (size_t)b * 4096;
#pragma unroll
      for (int i = 0; i < 2; i++) {
        const int idx = tid + 512 * i;
        sS[(idx >> 5) * L36 + (idx & 31)] =
            Sb[idx] + Sb[idx + 1024] + Sb[idx + 2048] + Sb[idx + 3072];
      }
    }
    if (tid < 16) sScal[tid] = 0.0f;
    const float v0 = scaleP[0] + V0EPS;
    __syncthreads();
    {  // w0 = Ainv0 * P[:,0]
      const float* xb = sPT + 32 * mq;
      float s = 0;
#pragma unroll
      for (int c = 0; c < 32; c++) s += areg[c] * xb[c];
      s += __shfl_xor(s, 1, 64); s += __shfl_xor(s, 2, 64);
      if (mq == 0) sW[SEG(mr)] = s;
    }
    __syncthreads();

#pragma unroll 1
    for (int t = 0; t < EE; ++t) {
      const bool hn = (t + 1 < EE);
      // ---- PH1: Pm = Ainv w ; dgw = G^T w ; qt = Y^T w ; S2 ----
      {
        const float* xb = sW + 40 * mq;
        float s = 0;
#pragma unroll
        for (int c = 0; c < 16; c++) s += areg[c] * xb[c];
#pragma unroll
        for (int c = 0; c < 16; c++) s += areg[16 + c] * xb[20 + c];
        s += __shfl_xor(s, 1, 64); s += __shfl_xor(s, 2, 64);
        if (mq == 0) sPm[SEG(mr)] = s;
      }
      if (tid < 256) {
        const int s8 = tid >> 3, p3 = tid & 7;
        if (s8 < t) {
          const float* gr = sGT + s8 * LTR + 16 * p3;
          const float* wr_ = sW + 20 * p3;
          float s = 0;
#pragma unroll
          for (int kk = 0; kk < 16; kk++) s += gr[kk] * wr_[kk];
          s += __shfl_xor(s, 1, 64); s += __shfl_xor(s, 2, 64); s += __shfl_xor(s, 4, 64);
          if (p3 == 0) sDgw[s8] = s;
        } else if (s8 == 31) {  // s8==31 never used by dgw: S2 here
          const float* wp = sW + 20 * p3;
          float s = 0;
#pragma unroll
          for (int kk = 0; kk < 16; kk++) s += wp[kk] * wp[kk];
          s += __shfl_xor(s, 1, 64); s += __shfl_xor(s, 2, 64); s += __shfl_xor(s, 4, 64);
          if (p3 == 0) sScal[SC_S2] = s;
        }
      } else {
        const int j = (tid - 256) >> 3, p3 = tid & 7;
        if (j < t) {
          const float* yr = sYT + j * LTR + 16 * p3;
          const float* wr_ = sW + 20 * p3;
          float s = 0;
#pragma unroll
          for (int kk = 0; kk < 16; kk++) s += yr[kk] * wr_[kk];
          s += __shfl_xor(s, 1, 64); s += __shfl_xor(s, 2, 64); s += __shfl_xor(s, 4, 64);
          if (p3 == 0) sQt[j] = s;
        }
      }
      __syncthreads();
      // ---- PH2: wU ; D_t ; Egg_t ; sigma ; KL ; R22 ----
      if (tid < 256) {  // wU[k] = v0 w[k] - sum_{j<t} Y[k][j] qt[j]
        const int k = tid >> 1, h = tid & 1;
        const float* yk = sYk + k * LKM + 16 * h;
        const float* qb = sQt + 16 * h;
        float a = 0;
#pragma unroll
        for (int u = 0; u < 16; u++) {
          const int j = 16 * h + u;
          a += (j < t) ? yk[u] * qb[u] : 0.0f;
        }
        a += __shfl_xor(a, 1, 64);
        if (h == 0) sWU[SEG(k)] = v0 * sW[SEG(k)] - a;
      } else if (tid < 384) {  // Egg append (k-major recurrence)
        const int k = tid - 256;
        float a = sW[SEG(k)];
        const float* ek = sEk + k * LKM;
        const int nc = (t + 3) >> 2;
#pragma unroll 1
        for (int c4 = 0; c4 < nc; ++c4) {
          const float4 ev = *(const float4*)(ek + 4 * c4);
          const float4 dv = *(const float4*)(sDgw + 4 * c4);
          const int u0 = 4 * c4;
          a -= ((u0 + 0 < t) ? ev.x * dv.x : 0.0f) + ((u0 + 1 < t) ? ev.y * dv.y : 0.0f) +
               ((u0 + 2 < t) ? ev.z * dv.z : 0.0f) + ((u0 + 3 < t) ? ev.w * dv.w : 0.0f);
        }
        sEk[k * LKM + t] = a;
        sEggT[t * LTR + k] = a;
      } else if (tid < 448) {  // wave 6: lanes<32: D append ; lanes>=32: R22 = w.Pm
        if (ln < 32) {
          const int r2 = ln;
          float a = (r2 == t) ? 1.0f : 0.0f;
          for (int s2 = 0; s2 < t; ++s2) a -= sDgw[s2] * sD[s2 * L36 + r2];
          sD[t * L36 + r2] = a;
        } else {
          const int k0 = (ln - 32) * 4;
          const float4 wv4 = *(const float4*)(sW + SEG(k0));
          const float4 pm4 = *(const float4*)(sPm + SEG(k0));
          float a = dot4(wv4, pm4);
          a = wsum32(a);
          if (ln == 32) sScal[SC_R22] = a;
        }
      } else {  // wave 7: sigma ; KL
        const float s2v = sScal[SC_S2];
        float a = (ln < t) ? sQt[ln] * sQt[ln] : 0.0f;
        a = wsum64(a);
        if (ln == 0) {
          sScal[SC_SIG] = v0 * s2v - a + 1.0f;
          sScal[SC_KL] += s2v;
        }
      }
      __syncthreads();
      // ---- PH3: Pu = Ainv wU ; dz ; B1 ; B2 ; R12 ; G/Y appends ----
      {
        const float* xb = sWU + 40 * mq;
        float s = 0;
#pragma unroll
        for (int c = 0; c < 16; c++) s += areg[c] * xb[c];
#pragma unroll
        for (int c = 0; c < 16; c++) s += areg[16 + c] * xb[20 + c];
        s += __shfl_xor(s, 1, 64); s += __shfl_xor(s, 2, 64);
        if (mq == 0) sPu[SEG(mr)] = s;
      }
      if (tid < 256) {  // dz[s4] = D[s4,:].S[:,t+1] - Egg^T[s4,:].P[:,t+1]
        const int s4 = tid >> 3, p3 = tid & 7;
        if (hn && s4 <= t) {
          const float* er = sEggT + s4 * LTR + 16 * p3;
          const float* pr = sPT + (t + 1) * PTS + 16 * p3;
          float a = 0;
#pragma unroll
          for (int kk = 0; kk < 16; kk++) a -= er[kk] * pr[kk];
          const float4 dv = *(const float4*)(sD + s4 * L36 + 4 * p3);
          const float4 sv = *(const float4*)(sS + (t + 1) * L36 + 4 * p3);  // S symmetric
          a += dot4(dv, sv);
          a += __shfl_xor(a, 1, 64); a += __shfl_xor(a, 2, 64); a += __shfl_xor(a, 4, 64);
          if (p3 == 0) sDz[s4] = a;
        }
      } else if (tid < 320) {  // wave 4: B2 = Egg_t . P[:,t]
        float a = sEggT[t * LTR + ln] * sPT[t * PTS + ln] +
                  sEggT[t * LTR + ln + 64] * sPT[t * PTS + ln + 64];
        a = wsum64(a);
        if (ln == 0) sScal[SC_B2] = a;
      } else if (tid < 384) {  // wave 5: lanes<32: B1 ; lanes>=32: R12 = wU.Pm
        if (ln < 32) {
          float a = sD[t * L36 + ln] * sS[t * L36 + ln];
          a = wsum32(a);
          if (ln == 0) sScal[SC_B1] = a;
        } else {
          const int k0 = (ln - 32) * 4;
          const float4 wu4 = *(const float4*)(sWU + SEG(k0));
          const float4 pm4 = *(const float4*)(sPm + SEG(k0));
          float a = dot4(wu4, pm4);
          a = wsum32(a);
          if (ln == 32) sScal[SC_R12] = a;
        }
      } else if (tid < 448) {  // wave 6: G/Y appends (both layouts)
        const float sig = sScal[SC_SIG];
        const float rsq = rsqrtf(sig);
#pragma unroll
        for (int u = 0; u < 2; u++) {
          const int k = ln + 64 * u;
          const float wu = sWU[SEG(k)];
          const float gv = wu / sig;
          const float yv = wu * rsq;
          sGT[t * LTR + k] = gv;
          sGk[k * LKM + t] = gv;
          sYT[t * LTR + k] = yv;
          sYk[k * LKM + t] = yv;
        }
      }
      __syncthreads();
      // ---- PH4: q_next ; R11 ----
      if (hn) {
        const float* gk = sGk + mr * LKM + 8 * mq;
        const float* dzb = sDz + 8 * mq;
        float a = 0;
#pragma unroll
        for (int u = 0; u < 8; u++) {
          const int s2 = 8 * mq + u;
          a += (s2 < t) ? gk[u] * dzb[u] : 0.0f;
        }
        a += __shfl_xor(a, 1, 64); a += __shfl_xor(a, 2, 64);
        if (mq == 0)
          sQ[SEG(mr)] = sPT[(t + 1) * PTS + mr] + a + (sWU[SEG(mr)] / sScal[SC_SIG]) * sDz[t];
      }
      if (wv == 0) {  // R11 = wU . Pu
        float a = sWU[SEG(ln)] * sPu[SEG(ln)] + sWU[SEG(ln + 64)] * sPu[SEG(ln + 64)];
        a = wsum64(a);
        if (ln == 0) sScal[SC_R11] = a;
      }
      __syncthreads();
      // ---- PH5: Ainv rank-2 update (per-thread scalar finalize) ; w_next ----
      {
        const float4 sc0 = *(const float4*)(sScal);      // S2, SIG, KL, B1
        const float4 sc1 = *(const float4*)(sScal + 4);  // B2, R11, R12, R22
        const float rs = 1.0f / sc0.y;
        const float beta = sc0.w - sc1.x - sc0.x;
        const float e11 = sc1.y * rs * rs;
        const float e12 = sc1.z * rs + 1.0f;
        const float e22 = sc1.w - beta;
        const float rd = 1.0f / (e11 * e22 - e12 * e12);
        const float t11 = e22 * rd, t12 = -e12 * rd, t22 = e11 * rd;
        const float u1r = sPu[SEG(mr)] * rs, u2r = sPm[SEG(mr)];
        const float* pub = sPu + 40 * mq;
        const float* pmb = sPm + 40 * mq;
#pragma unroll
        for (int c = 0; c < 16; c++) {
          const float u1c = pub[c] * rs;
          const float u2c = pmb[c];
          areg[c] -= u1r * (t11 * u1c + t12 * u2c) + u2r * (t12 * u1c + t22 * u2c);
        }
#pragma unroll
        for (int c = 0; c < 16; c++) {
          const float u1c = pub[20 + c] * rs;
          const float u2c = pmb[20 + c];
          areg[16 + c] -= u1r * (t11 * u1c + t12 * u2c) + u2r * (t12 * u1c + t22 * u2c);
        }
      }
      if (hn) {
        const float* xb = sQ + 40 * mq;
        float s = 0;
#pragma unroll
        for (int c = 0; c < 16; c++) s += areg[c] * xb[c];
#pragma unroll
        for (int c = 0; c < 16; c++) s += areg[16 + c] * xb[20 + c];
        s += __shfl_xor(s, 1, 64); s += __shfl_xor(s, 2, 64);
        if (mq == 0) sW[SEG(mr)] = s;
      }
      __syncthreads();
    }

    // ================= fused postA =================
    float* sR1T  = uni2;         // [32][36]  (over dead sYT)
    float* sGamT = uni2 + 1152;  // [32][36]
    float* sRhsT = uni1;         // [32][132] (over dead sYk)
    float* sWrT  = uni3;         // [32][132] (over sGk -- dead after PA1)
    if (tid == 0) wsKL[b] = sScal[SC_KL];

    // ---- PA0: R1T[e][s] = D[s,:].S[e,:] - EggT[s,:].PT[e,:] ----
#pragma unroll
    for (int h = 0; h < 2; ++h) {
      const int lin = tid + 512 * h, s = lin >> 5, e = lin & 31;
      const float4* er = (const float4*)(sEggT + s * LTR);
      const float4* pr = (const float4*)(sPT + e * PTS);
      float a = 0;
#pragma unroll 8
      for (int u = 0; u < 32; ++u) a -= dot4(er[u], pr[u]);
      const float4* dr = (const float4*)(sD + s * L36);
      const float4* sr = (const float4*)(sS + e * L36);
#pragma unroll
      for (int u = 0; u < 8; ++u) a += dot4(dr[u], sr[u]);
      sR1T[e * 36 + s] = a;
    }
    __syncthreads();
    // ---- PA1: RhsT[e][k] = PT[e][k] + sum_s G[k][s] R1T[e][s] ----
    {
      const int k = tid & 127, e4 = tid >> 7;
      float4 g0, g1, g2, g3, g4, g5, g6, g7;
      {
        const float4* gk = (const float4*)(sGk + k * LKM);
        g0 = gk[0]; g1 = gk[1]; g2 = gk[2]; g3 = gk[3];
        g4 = gk[4]; g5 = gk[5]; g6 = gk[6]; g7 = gk[7];
      }
#pragma unroll
      for (int u = 0; u < 8; ++u) {
        const int e = e4 * 8 + u;
        const float4* r1 = (const float4*)(sR1T + e * 36);
        float a = sPT[e * PTS + k];
        a += dot4(g0, r1[0]) + dot4(g1, r1[1]) + dot4(g2, r1[2]) + dot4(g3, r1[3]);
        a += dot4(g4, r1[4]) + dot4(g5, r1[5]) + dot4(g6, r1[6]) + dot4(g7, r1[7]);
        sRhsT[e * PTS + k] = a;
      }
    }
    __syncthreads();
    // ---- PA2: WrT[e][k] = AinvP . rhs[:,e]  (areg matvec, 32 episodes) ----
#pragma unroll 2
    for (int e = 0; e < EE; ++e) {
      const float* xb = sRhsT + e * PTS + 32 * mq;
      float s = 0;
#pragma unroll
      for (int c = 0; c < 32; c++) s += areg[c] * xb[c];
      s += __shfl_xor(s, 1, 64); s += __shfl_xor(s, 2, 64);
      if (mq == 0) sWrT[e * PTS + mr] = s;
    }
    __syncthreads();
    // ---- PA3: GamT[e][s] = GT[s,:].WrT[e,:] ----
#pragma unroll
    for (int h = 0; h < 2; ++h) {
      const int lin = tid + 512 * h, s = lin >> 5, e = lin & 31;
      const float4* gr = (const float4*)(sGT + s * LTR);
      const float4* wr = (const float4*)(sWrT + e * PTS);
      float a = 0;
#pragma unroll 8
      for (int u = 0; u < 32; ++u) a += dot4(gr[u], wr[u]);
      sGamT[e * 36 + s] = a;
    }
    __syncthreads();
    // ---- PA4: Wc -> wsWt rows 0..127 ; Vc -> rows 128..159 ; KLr ----
    {
      const int k = tid & 127, e4 = tid >> 7;
      float4 E0, E1, E2, E3, E4, E5, E6, E7;
      {
        const float4* ek = (const float4*)(sEk + k * LKM);
        E0 = ek[0]; E1 = ek[1]; E2 = ek[2]; E3 = ek[3];
        E4 = ek[4]; E5 = ek[5]; E6 = ek[6]; E7 = ek[7];
      }
#pragma unroll
      for (int u = 0; u < 8; ++u) {
        const int e = e4 * 8 + u;
        const float4* gm = (const float4*)(sGamT + e * 36);
        float a = sWrT[e * PTS + k];
        a -= dot4(E0, gm[0]) + dot4(E1, gm[1]) + dot4(E2, gm[2]) + dot4(E3, gm[3]);
        a -= dot4(E4, gm[4]) + dot4(E5, gm[5]) + dot4(E6, gm[6]) + dot4(E7, gm[7]);
        wsWt[(size_t)b * 5120 + e * 160 + k] = a;
      }
    }
    {  // Vc[e][sp] = sum_f D[f][sp] * GamT[e][f]
      const int e = tid & 31, sp = tid >> 5;  // sp in 0..15, handle sp and sp+16
      float4 gm[8];
      {
        const float4* g4 = (const float4*)(sGamT + e * 36);
#pragma unroll
        for (int u = 0; u < 8; ++u) gm[u] = g4[u];
      }
#pragma unroll
      for (int h = 0; h < 2; ++h) {
        const int sp2 = sp + 16 * h;
        float a = 0;
#pragma unroll
        for (int u = 0; u < 8; ++u) {
          const float4 g = gm[u];
          a += sD[(4 * u + 0) * L36 + sp2] * g.x + sD[(4 * u + 1) * L36 + sp2] * g.y +
               sD[(4 * u + 2) * L36 + sp2] * g.z + sD[(4 * u + 3) * L36 + sp2] * g.w;
        }
        wsWt[(size_t)b * 5120 + e * 160 + 128 + sp2] = a;
      }
    }
    {  // KLr[e] = sum_k Wr[k][e]^2
      const int e = tid >> 4, p = tid & 15;
      const float4* wr = (const float4*)(sWrT + e * PTS + 8 * p);
      const float4 w0 = wr[0], w1 = wr[1];
      float a = dot4(w0, w0) + dot4(w1, w1);
      a += __shfl_xor(a, 1, 64); a += __shfl_xor(a, 2, 64);
      a += __shfl_xor(a, 4, 64); a += __shfl_xor(a, 8, 64);
      if (p == 0) wsKLr[b * EE + e] = a;
    }
    __threadfence();  // device-scope visibility of wsWt/wsKL/wsKLr across XCDs
  }

  cg::this_grid().sync();

  // ================= Phase D: postB quarter (all 256 WGs) + final (WG 0) =================
  {
    float* sWtT = SM;            // [32][176]
    float* Mch  = SM + 5632;     // 2*16*132
    const int b = blockIdx.x >> 2, cq = blockIdx.x & 3;
    {
      // wsWt is [b][e][160]: direct (no transpose) load
      const int e = tid >> 4, j = tid & 15;
      const float* Wg = wsWt + (size_t)b * 5120 + e * 160;
#pragma unroll
      for (int u = 0; u < 10; ++u) sWtT[e * LWT + j + 16 * u] = Wg[j + 16 * u];
    }
    const int srow = tid >> 5, sc4 = tid & 31;  // stage: 16 rows x 32 float4 (128 cols)
    const int e = tid & 31, cs = tid >> 5;      // compute: episode e, col-octet cs
    const float* xb = x + (size_t)b * EE * CC;
    const int cbase = cq * 128;
    float4 st = *(const float4*)(M0 + srow * CC + cbase + 4 * sc4);  // ch2=0 rows are all M0
    float acc[8];
#pragma unroll
    for (int u = 0; u < 8; u++) acc[u] = 0.0f;
    int buf = 0;
#pragma unroll 1
    for (int ch2 = 0; ch2 < 10; ++ch2) {
      *(float4*)(Mch + buf * 2112 + srow * 132 + 4 * sc4) = st;
      __syncthreads();
      if (ch2 + 1 < 10) {
        const int row = (ch2 + 1) * 16 + srow;
        st = (row < 128) ? *(const float4*)(M0 + row * CC + cbase + 4 * sc4)
                         : *(const float4*)(xb + (row - 128) * CC + cbase + 4 * sc4);
      }
      const float4* wt4 = (const float4*)(sWtT + e * LWT + ch2 * 16);
      const float4 wa = wt4[0], wb = wt4[1], wc = wt4[2], wd = wt4[3];
      const float wv16[16] = {wa.x, wa.y, wa.z, wa.w, wb.x, wb.y, wb.z, wb.w,
                              wc.x, wc.y, wc.z, wc.w, wd.x, wd.y, wd.z, wd.w};
#pragma unroll
      for (int kk = 0; kk < 16; ++kk) {
        const float* mrp = Mch + buf * 2112 + kk * 132 + cs * 8;
        const float4 m0 = *(const float4*)(mrp);
        const float4 m1 = *(const float4*)(mrp + 4);
        const float wk = wv16[kk];
        acc[0] += wk * m0.x; acc[1] += wk * m0.y; acc[2] += wk * m0.z; acc[3] += wk * m0.w;
        acc[4] += wk * m1.x; acc[5] += wk * m1.y; acc[6] += wk * m1.z; acc[7] += wk * m1.w;
      }
      buf ^= 1;
    }
    {
      const size_t ob = ((size_t)b * EE + e) * CC + cbase + cs * 8;
      const size_t nb = ((size_t)e * BB + b) * CC + cbase + cs * 8;
#pragma unroll
      for (int u = 0; u < 2; u++) {
        const float4 nz = *(const float4*)(znoise + nb + 4 * u);
        float4 o;
        o.x = acc[4 * u] + nz.x;     o.y = acc[4 * u + 1] + nz.y;
        o.z = acc[4 * u + 2] + nz.z; o.w = acc[4 * u + 3] + nz.w;
        *(float4*)(out + ob + 4 * u) = o;
      }
    }
  }

  if (blockIdx.x == 0) {
    // ======== final: total divergence (inputs written in Phase C, pre-sync) ========
    float* sPp = SM + 9856;  // past sWtT+Mch, no overlap with live Phase-D data
    __syncthreads();
    float s = 0.0f;
    if (tid < 64) s += wsKL[tid];
    for (int i = tid; i < 2048; i += 512) s += wsKLr[i];
    sPp[tid] = s;
    __syncthreads();
    for (int off = 256; off > 0; off >>= 1) {
      if (tid < off) sPp[tid] += sPp[tid + off];
      __syncthreads();
    }
    if (tid == 0) {
      const float lws = lwsP[0];
      const float sw2 = expf(2.0f * lws);
      out[(size_t)BB * EE * CC] =
          0.5f * sPp[0] / (float)(EE * BB) + (float)KK * (sw2 - 1.0f - 2.0f * lws);
    }
  }
}

extern "C" void kernel_launch(void* const* d_in, const int* in_sizes, int n_in,
                              void* d_out, int out_size, void* d_ws, size_t ws_size,
                              hipStream_t stream) {
  (void)in_sizes; (void)n_in; (void)out_size; (void)ws_size;
  const float* x = (const float*)d_in[0];        // [B,E,C]
  const float* M0 = (const float*)d_in[1];       // [K,C]
  const float* scaleP = (const float*)d_in[2];   // scalar
  const float* lwsP = (const float*)d_in[3];     // scalar
  const float* znoise = (const float*)d_in[4];   // [E,B,C]
  float* out = (float*)d_out;

  float* ws = (float*)d_ws;
  float* wsP = ws;                        // 262144
  float* wsSp = wsP + 262144;             // 262144 (64 x 4 partials x 1024)
  float* wsA0 = wsSp + 262144;            // 16384
  float* wsAinv0 = wsA0 + 16384;          // 16384
  float* wsKL = wsAinv0 + 16384;          // 64
  float* wsKLr = wsKL + 64;               // 2048
  float* wsWt = wsKLr + 2048;             // 327680 (64 x 32 x 160, [b][e][row])

  a0_kernel<<<512, 256, 0, stream>>>(M0, wsA0);
  psinv_kernel<<<257, 1024, 0, stream>>>(x, M0, wsP, wsSp, wsA0, wsAinv0);

  const float* Pg = wsP;
  const float* Sg = wsSp;
  const float* Ainv0c = wsAinv0;
  void* kargs[12] = {
      (void*)&Pg, (void*)&Sg, (void*)&scaleP, (void*)&Ainv0c,
      (void*)&wsKL, (void*)&wsKLr, (void*)&wsWt,
      (void*)&x, (void*)&M0, (void*)&znoise, (void*)&lwsP, (void*)&out};
  hipLaunchCooperativeKernel((void*)scanpost_kernel, dim3(256), dim3(512),
                             kargs, 0, stream);
}

// Round 10
// 261.299 us; speedup vs baseline: 1.1803x; 1.1803x over previous
//
#include <hip/hip_runtime.h>

// (B,E,K,C) = (64,32,128,512), fp32.
#define BB 64
#define EE 32
#define KK 128
#define CC 512
#define V0EPS 1e-7f

#define LTR 132   // [32][132] padded stride
#define PTS 132   // scan: P^T / RhsT / WrT row stride
#define LKM 36    // scan: k-major row stride (G/Y/Egg)
#define L36 36    // scan: S/D row stride
#define LWT 176   // postB: Wt^T row stride
// segment-padded K-vector layout: element i lives at (i/16)*20 + (i%16)
#define SEG(i) ((((i) >> 4) * 20) + ((i) & 15))

// scan sScal slots (order matters: read as two float4s in PH5)
#define SC_S2  0
#define SC_SIG 1
#define SC_KL  2
#define SC_B1  3
#define SC_B2  4
#define SC_R11 5
#define SC_R12 6
#define SC_R22 7

__device__ __forceinline__ float wsum64(float v) {
#pragma unroll
  for (int m = 32; m >= 1; m >>= 1) v += __shfl_xor(v, m, 64);
  return v;
}

__device__ __forceinline__ float wsum32(float v) {  // reduce within aligned 32-lane half
#pragma unroll
  for (int m = 16; m >= 1; m >>= 1) v += __shfl_xor(v, m, 64);
  return v;
}

__device__ __forceinline__ float dot4(const float4 a, const float4 b) {
  return a.x * b.x + a.y * b.y + a.z * b.z + a.w * b.w;
}

// ---------------- Kernel 1: A0 = M0 M0^T + I (512 WGs: k x l-quarter) ----------------
__global__ __launch_bounds__(256) void a0_kernel(const float* __restrict__ M0,
                                                 float* __restrict__ wsA0) {
  __shared__ __align__(16) float sRow[CC];
  const int k = blockIdx.x >> 2, quarter = blockIdx.x & 3;
  for (int c = threadIdx.x; c < CC; c += 256) sRow[c] = M0[k * CC + c];
  __syncthreads();
  const int wv = threadIdx.x >> 6, ln = threadIdx.x & 63;
  const float4* zr = (const float4*)(sRow + 8 * ln);
  const float4 z0 = zr[0], z1 = zr[1];
  for (int li = 0; li < 8; ++li) {
    const int l = quarter * 32 + wv * 8 + li;
    const float4* rp = (const float4*)(M0 + l * CC + 8 * ln);
    const float4 a = rp[0], b = rp[1];
    float s = dot4(a, z0) + dot4(b, z1);
    s = wsum64(s);
    if (ln == 0) wsA0[k * KK + l] = s + (l == k ? 1.0f : 0.0f);
  }
}

// ------- Kernel 2: block 0 -> inv(A0) via 4-pivot GJ ; blocks 1..256 -> P/S partials -------
__global__ __launch_bounds__(1024) void psinv_kernel(const float* __restrict__ x,
                                                     const float* __restrict__ M0,
                                                     float* __restrict__ wsP,
                                                     float* __restrict__ wsSp,
                                                     const float* __restrict__ A0g,
                                                     float* __restrict__ Ainv0) {
  __shared__ __align__(16) float zAll[32][520];
  __shared__ __align__(16) float Mch[2][16][520];
  __shared__ __align__(16) float sFb[2][4][128];   // [buf][col j+i][row]
  __shared__ __align__(16) float sPv[2][4][256];   // [buf][row j+i][A-part 128 | I-part 128]
  const int tid = threadIdx.x;

  if (blockIdx.x > 0) {
    // ================= ps body: P rows kq*32..kq*32+31 ; S partial over c-quarter =================
    const int b = (blockIdx.x - 1) >> 2, kq = (blockIdx.x - 1) & 3;
    {
      const float4* x4 = (const float4*)(x + (size_t)b * EE * CC);
#pragma unroll
      for (int i = 0; i < 4; i++) {
        const int F = tid + 1024 * i, e = F >> 7, c4 = F & 127;
        ((float4*)zAll[e])[c4] = x4[F];
      }
    }
    const float4* M4 = (const float4*)M0;
    const int srow = tid >> 7, sc4 = tid & 127;
    const int kbase = kq * 32;
    float4 st0 = M4[(kbase + srow) * 128 + sc4];
    float4 st1 = M4[(kbase + 8 + srow) * 128 + sc4];
    int buf = 0;
    const int p = tid & 7;           // 8 threads per dot
    const int ep = (tid >> 3) & 15;  // episodes 2*ep, 2*ep+1  (0..31)
    const int kp = tid >> 7;         // k rows kp, kp+8
#pragma unroll 1
    for (int kc = 0; kc < 2; ++kc) {
      ((float4*)Mch[buf][srow])[sc4] = st0;
      ((float4*)Mch[buf][8 + srow])[sc4] = st1;
      __syncthreads();
      if (kc == 0) {
        st0 = M4[(kbase + 16 + srow) * 128 + sc4];
        st1 = M4[(kbase + 24 + srow) * 128 + sc4];
      }
      float s00 = 0, s01 = 0, s10 = 0, s11 = 0;
      const float* m0 = Mch[buf][kp];
      const float* m1 = Mch[buf][kp + 8];
      const float* z0 = zAll[2 * ep];
      const float* z1 = zAll[2 * ep + 1];
#pragma unroll
      for (int u = 0; u < 16; u++) {
        const int c = 4 * p + 32 * u;
        const float4 a0 = *(const float4*)(m0 + c);
        const float4 a1 = *(const float4*)(m1 + c);
        const float4 b0 = *(const float4*)(z0 + c);
        const float4 b1 = *(const float4*)(z1 + c);
        s00 += dot4(a0, b0); s01 += dot4(a0, b1);
        s10 += dot4(a1, b0); s11 += dot4(a1, b1);
      }
#pragma unroll
      for (int m = 1; m <= 4; m <<= 1) {
        s00 += __shfl_xor(s00, m, 64); s01 += __shfl_xor(s01, m, 64);
        s10 += __shfl_xor(s10, m, 64); s11 += __shfl_xor(s11, m, 64);
      }
      if (p == 0) {
        float* Pb = wsP + (size_t)b * KK * EE;
        Pb[(kbase + kc * 16 + kp) * EE + 2 * ep] = s00;
        Pb[(kbase + kc * 16 + kp) * EE + 2 * ep + 1] = s01;
        Pb[(kbase + kc * 16 + kp + 8) * EE + 2 * ep] = s10;
        Pb[(kbase + kc * 16 + kp + 8) * EE + 2 * ep + 1] = s11;
      }
      buf ^= 1;
    }
    // S partial = Z[:, cq] Z[:, cq]^T
    {
      const int e = tid >> 5, f = tid & 31;
      const float4* ze = ((const float4*)zAll[e]) + 32 * kq;
      const float4* zf = ((const float4*)zAll[f]) + 32 * kq;
      float a0 = 0, a1 = 0, a2 = 0, a3 = 0;
#pragma unroll 4
      for (int u = 0; u < 32; u++) {
        const float4 A = ze[u], Bq = zf[u];
        a0 += A.x * Bq.x; a1 += A.y * Bq.y; a2 += A.z * Bq.z; a3 += A.w * Bq.w;
      }
      wsSp[((size_t)b * 4 + kq) * 1024 + e * EE + f] = (a0 + a1) + (a2 + a3);
    }
  } else {
    // ======== inv0 body (block 0): 4-pivot register GJ, 32 super-iterations ========
    const int r = tid >> 3, q = tid & 7;
    float wreg[16], vreg[16];
    {
      const float4* a4 = (const float4*)(A0g + r * KK + 16 * q);
#pragma unroll
      for (int u = 0; u < 4; u++) {
        const float4 t4 = a4[u];
        wreg[4 * u] = t4.x; wreg[4 * u + 1] = t4.y; wreg[4 * u + 2] = t4.z; wreg[4 * u + 3] = t4.w;
      }
#pragma unroll
      for (int c = 0; c < 16; c++) vreg[c] = (16 * q + c == r) ? 1.0f : 0.0f;
    }
    // prologue: stage cols 0..3 and rows 0..3
    if (q == 0) {
      sFb[0][0][r] = wreg[0]; sFb[0][1][r] = wreg[1];
      sFb[0][2][r] = wreg[2]; sFb[0][3][r] = wreg[3];
    }
    if (r < 4) {
#pragma unroll
      for (int c = 0; c < 16; c++) {
        sPv[0][r][16 * q + c] = wreg[c];
        sPv[0][r][128 + 16 * q + c] = vreg[c];
      }
    }
    __syncthreads();
#pragma unroll 1
    for (int jj = 0; jj < 32; ++jj) {
      const int j = 4 * jj, db = jj & 1, dn = db ^ 1;
      const float* c0 = sFb[db][0];
      const float* c1 = sFb[db][1];
      const float* c2 = sFb[db][2];
      const float* c3 = sFb[db][3];
      const float* r0 = sPv[db][0];
      const float* r1 = sPv[db][1];
      const float* r2 = sPv[db][2];
      const float* r3 = sPv[db][3];
      const float p00 = c0[j],     p01 = c1[j],     p02 = c2[j],     p03 = c3[j];
      const float p10 = c0[j + 1], p11 = c1[j + 1], p12 = c2[j + 1], p13 = c3[j + 1];
      const float p20 = c0[j + 2], p21 = c1[j + 2], p22 = c2[j + 2], p23 = c3[j + 2];
      const float p30 = c0[j + 3], p31 = c1[j + 3], p32 = c2[j + 3], p33 = c3[j + 3];
      const float rp00 = 1.0f / p00;
      const float g10 = p10 * rp00;
      const float q11 = p11 - g10 * p01, q12 = p12 - g10 * p02, q13 = p13 - g10 * p03;
      const float rq11 = 1.0f / q11;
      const float g20 = p20 * rp00;
      const float g21 = (p21 - g20 * p01) * rq11;
      const float q22 = p22 - g20 * p02 - g21 * q12;
      const float q23 = p23 - g20 * p03 - g21 * q13;
      const float rq22 = 1.0f / q22;
      const float g30 = p30 * rp00;
      const float g31 = (p31 - g30 * p01) * rq11;
      const float g32 = (p32 - g30 * p02 - g31 * q12) * rq22;
      const float q33 = p33 - g30 * p03 - g31 * q13 - g32 * q23;
      const float rq33 = 1.0f / q33;
      const float f0 = (r == j) ? 0.0f : c0[r] * rp00;
      const float f1 = (r == j + 1) ? 0.0f : (c1[r] - f0 * p01) * rq11;
      const float f2 = (r == j + 2) ? 0.0f : (c2[r] - f0 * p02 - f1 * q12) * rq22;
      const float f3 = (r == j + 3) ? 0.0f : (c3[r] - f0 * p03 - f1 * q13 - f2 * q23) * rq33;
      const float cc3 = f3;
      const float cc2 = f2 - cc3 * g32;
      const float cc1 = f1 - cc2 * g21 - cc3 * g31;
      const float cc0 = f0 - cc1 * g10 - cc2 * g20 - cc3 * g30;
      if (16 * q + 15 >= j) {  // A-part: only cols >= j are touched
        const float4* w0 = (const float4*)(r0 + 16 * q);
        const float4* w1 = (const float4*)(r1 + 16 * q);
        const float4* w2 = (const float4*)(r2 + 16 * q);
        const float4* w3 = (const float4*)(r3 + 16 * q);
#pragma unroll
        for (int u = 0; u < 4; u++) {
          const float4 a0 = w0[u], a1 = w1[u], a2 = w2[u], a3 = w3[u];
          wreg[4 * u]     -= cc0 * a0.x + cc1 * a1.x + cc2 * a2.x + cc3 * a3.x;
          wreg[4 * u + 1] -= cc0 * a0.y + cc1 * a1.y + cc2 * a2.y + cc3 * a3.y;
          wreg[4 * u + 2] -= cc0 * a0.z + cc1 * a1.z + cc2 * a2.z + cc3 * a3.z;
          wreg[4 * u + 3] -= cc0 * a0.w + cc1 * a1.w + cc2 * a2.w + cc3 * a3.w;
        }
      }
      if (16 * q <= j + 3) {  // I-part: staged rows' I-support is cols <= j+3
        const float4* v0 = (const float4*)(r0 + 128 + 16 * q);
        const float4* v1 = (const float4*)(r1 + 128 + 16 * q);
        const float4* v2 = (const float4*)(r2 + 128 + 16 * q);
        const float4* v3 = (const float4*)(r3 + 128 + 16 * q);
#pragma unroll
        for (int u = 0; u < 4; u++) {
          const float4 a0 = v0[u], a1 = v1[u], a2 = v2[u], a3 = v3[u];
          vreg[4 * u]     -= cc0 * a0.x + cc1 * a1.x + cc2 * a2.x + cc3 * a3.x;
          vreg[4 * u + 1] -= cc0 * a0.y + cc1 * a1.y + cc2 * a2.y + cc3 * a3.y;
          vreg[4 * u + 2] -= cc0 * a0.z + cc1 * a1.z + cc2 * a2.z + cc3 * a3.z;
          vreg[4 * u + 3] -= cc0 * a0.w + cc1 * a1.w + cc2 * a2.w + cc3 * a3.w;
        }
      }
      if (jj + 1 < 32) {  // stage cols/rows j+4..j+7 (post-update values)
#pragma unroll
        for (int i = 0; i < 4; ++i) {
          const int j2 = j + 4 + i;
          float wv_ = 0.0f;
#pragma unroll
          for (int c = 0; c < 16; c++) if (c == (j2 & 15)) wv_ = wreg[c];
          if (q == (j2 >> 4)) sFb[dn][i][r] = wv_;
          if (r == j2) {
#pragma unroll
            for (int c = 0; c < 16; c++) {
              sPv[dn][i][16 * q + c] = wreg[c];
              sPv[dn][i][128 + 16 * q + c] = vreg[c];
            }
          }
        }
      }
      __syncthreads();
    }
    {
      float dval = 0.0f;
#pragma unroll
      for (int c = 0; c < 16; c++) if (c == (r & 15)) dval = wreg[c];
      if (q == (r >> 4)) sFb[0][0][r] = dval;
    }
    __syncthreads();
    {
      const float sc = 1.0f / sFb[0][0][r];
      float4* o4 = (float4*)(Ainv0 + r * KK + 16 * q);
#pragma unroll
      for (int u = 0; u < 4; u++) {
        float4 o;
        o.x = vreg[4 * u] * sc; o.y = vreg[4 * u + 1] * sc;
        o.z = vreg[4 * u + 2] * sc; o.w = vreg[4 * u + 3] * sc;
        o4[u] = o;
      }
    }
  }
}

// ---------------- Kernel 3: scan + fused postA, 512 threads, one WG per batch ----------------
// (R4's verified 8-wave version: DS-pipe-bound phases, fewer waves behind each barrier;
//  postA fused with AinvP in areg and b128-friendly LDS layouts.)
__global__ __launch_bounds__(512) void scan_kernel(
    const float* __restrict__ Pg, const float* __restrict__ Sg,  // Sg = 4 partials per batch
    const float* __restrict__ scaleP, const float* __restrict__ Ainv0,
    float* __restrict__ wsKL, float* __restrict__ wsKLr, float* __restrict__ wsWt) {
  __shared__ __align__(16) float sPT[EE * PTS];    // P^T : [e][k]
  __shared__ __align__(16) float sGT[EE * LTR];    // G^T : [t][k]
  __shared__ __align__(16) float sEggT[EE * LTR];  // Egg^T : [t][k]
  __shared__ __align__(16) float uni2[EE * LTR];   // scan: Y^T [t][k] | postA: R1T + GamT
  __shared__ __align__(16) float uni3[KK * LKM];   // scan: G [k][t]  | postA: WrT [e][k]
  __shared__ __align__(16) float uni1[KK * LKM];   // scan: Y [k][j]  | postA: RhsT [e][k]
  __shared__ __align__(16) float sEk[KK * LKM];    // Egg: [k][s]
  __shared__ __align__(16) float sS[EE * L36];     // S (symmetric)
  __shared__ __align__(16) float sD[EE * L36];     // D : [s][r2]
  __shared__ __align__(16) float sW[160];
  __shared__ __align__(16) float sWU[160];
  __shared__ __align__(16) float sPu[160];
  __shared__ __align__(16) float sPm[160];
  __shared__ __align__(16) float sQ[160];
  __shared__ __align__(16) float sDz[EE];
  __shared__ __align__(16) float sDgw[EE];
  __shared__ __align__(16) float sQt[EE];
  __shared__ __align__(16) float sScal[16];

  float* sYT = uni2;
  float* sGk = uni3;
  float* sYk = uni1;

  const int tid = threadIdx.x, wv = tid >> 6, ln = tid & 63;
  const int mr = tid >> 2, mq = tid & 3;  // matvec: row mr, col-quarter mq
  const int b = blockIdx.x;

  float areg[32];
  {
    const float4* a4 = (const float4*)(Ainv0 + mr * KK + 32 * mq);
#pragma unroll
    for (int u = 0; u < 8; u++) {
      const float4 t4 = a4[u];
      areg[4 * u] = t4.x; areg[4 * u + 1] = t4.y; areg[4 * u + 2] = t4.z; areg[4 * u + 3] = t4.w;
    }
  }
  {
    const float* Pb = Pg + (size_t)b * KK * EE;
#pragma unroll
    for (int i = 0; i < 8; i++) {
      const int idx = tid + 512 * i;                  // idx = k*32 + e
      sPT[(idx & 31) * PTS + (idx >> 5)] = Pb[idx];   // transpose into [e][k]
    }
    const float* Sb = Sg + (size_t)b * 4096;
#pragma unroll
    for (int i = 0; i < 2; i++) {
      const int idx = tid + 512 * i;
      sS[(idx >> 5) * L36 + (idx & 31)] =
          Sb[idx] + Sb[idx + 1024] + Sb[idx + 2048] + Sb[idx + 3072];
    }
  }
  if (tid < 16) sScal[tid] = 0.0f;
  const float v0 = scaleP[0] + V0EPS;
  __syncthreads();
  {  // w0 = Ainv0 * P[:,0]
    const float* xb = sPT + 32 * mq;
    float s = 0;
#pragma unroll
    for (int c = 0; c < 32; c++) s += areg[c] * xb[c];
    s += __shfl_xor(s, 1, 64); s += __shfl_xor(s, 2, 64);
    if (mq == 0) sW[SEG(mr)] = s;
  }
  __syncthreads();

#pragma unroll 1
  for (int t = 0; t < EE; ++t) {
    const bool hn = (t + 1 < EE);
    // ---- PH1: Pm = Ainv w ; dgw = G^T w ; qt = Y^T w ; S2 ----
    {
      const float* xb = sW + 40 * mq;
      float s = 0;
#pragma unroll
      for (int c = 0; c < 16; c++) s += areg[c] * xb[c];
#pragma unroll
      for (int c = 0; c < 16; c++) s += areg[16 + c] * xb[20 + c];
      s += __shfl_xor(s, 1, 64); s += __shfl_xor(s, 2, 64);
      if (mq == 0) sPm[SEG(mr)] = s;
    }
    if (tid < 256) {
      const int s8 = tid >> 3, p3 = tid & 7;
      if (s8 < t) {
        const float* gr = sGT + s8 * LTR + 16 * p3;
        const float* wr_ = sW + 20 * p3;
        float s = 0;
#pragma unroll
        for (int kk = 0; kk < 16; kk++) s += gr[kk] * wr_[kk];
        s += __shfl_xor(s, 1, 64); s += __shfl_xor(s, 2, 64); s += __shfl_xor(s, 4, 64);
        if (p3 == 0) sDgw[s8] = s;
      } else if (s8 == 31) {  // s8==31 never used by dgw: S2 here
        const float* wp = sW + 20 * p3;
        float s = 0;
#pragma unroll
        for (int kk = 0; kk < 16; kk++) s += wp[kk] * wp[kk];
        s += __shfl_xor(s, 1, 64); s += __shfl_xor(s, 2, 64); s += __shfl_xor(s, 4, 64);
        if (p3 == 0) sScal[SC_S2] = s;
      }
    } else {
      const int j = (tid - 256) >> 3, p3 = tid & 7;
      if (j < t) {
        const float* yr = sYT + j * LTR + 16 * p3;
        const float* wr_ = sW + 20 * p3;
        float s = 0;
#pragma unroll
        for (int kk = 0; kk < 16; kk++) s += yr[kk] * wr_[kk];
        s += __shfl_xor(s, 1, 64); s += __shfl_xor(s, 2, 64); s += __shfl_xor(s, 4, 64);
        if (p3 == 0) sQt[j] = s;
      }
    }
    __syncthreads();
    // ---- PH2: wU ; D_t ; Egg_t ; sigma ; KL ; R22 ----
    if (tid < 256) {  // wU[k] = v0 w[k] - sum_{j<t} Y[k][j] qt[j]
      const int k = tid >> 1, h = tid & 1;
      const float* yk = sYk + k * LKM + 16 * h;
      const float* qb = sQt + 16 * h;
      float a = 0;
#pragma unroll
      for (int u = 0; u < 16; u++) {
        const int j = 16 * h + u;
        a += (j < t) ? yk[u] * qb[u] : 0.0f;
      }
      a += __shfl_xor(a, 1, 64);
      if (h == 0) sWU[SEG(k)] = v0 * sW[SEG(k)] - a;
    } else if (tid < 384) {  // Egg append (k-major recurrence)
      const int k = tid - 256;
      float a = sW[SEG(k)];
      const float* ek = sEk + k * LKM;
      const int nc = (t + 3) >> 2;
#pragma unroll 1
      for (int c4 = 0; c4 < nc; ++c4) {
        const float4 ev = *(const float4*)(ek + 4 * c4);
        const float4 dv = *(const float4*)(sDgw + 4 * c4);
        const int u0 = 4 * c4;
        a -= ((u0 + 0 < t) ? ev.x * dv.x : 0.0f) + ((u0 + 1 < t) ? ev.y * dv.y : 0.0f) +
             ((u0 + 2 < t) ? ev.z * dv.z : 0.0f) + ((u0 + 3 < t) ? ev.w * dv.w : 0.0f);
      }
      sEk[k * LKM + t] = a;
      sEggT[t * LTR + k] = a;
    } else if (tid < 448) {  // wave 6: lanes<32: D append ; lanes>=32: R22 = w.Pm
      if (ln < 32) {
        const int r2 = ln;
        float a = (r2 == t) ? 1.0f : 0.0f;
        for (int s2 = 0; s2 < t; ++s2) a -= sDgw[s2] * sD[s2 * L36 + r2];
        sD[t * L36 + r2] = a;
      } else {
        const int k0 = (ln - 32) * 4;
        const float4 wv4 = *(const float4*)(sW + SEG(k0));
        const float4 pm4 = *(const float4*)(sPm + SEG(k0));
        float a = dot4(wv4, pm4);
        a = wsum32(a);
        if (ln == 32) sScal[SC_R22] = a;
      }
    } else {  // wave 7: sigma ; KL
      const float s2v = sScal[SC_S2];
      float a = (ln < t) ? sQt[ln] * sQt[ln] : 0.0f;
      a = wsum64(a);
      if (ln == 0) {
        sScal[SC_SIG] = v0 * s2v - a + 1.0f;
        sScal[SC_KL] += s2v;
      }
    }
    __syncthreads();
    // ---- PH3: Pu = Ainv wU ; dz ; B1 ; B2 ; R12 ; G/Y appends ----
    {
      const float* xb = sWU + 40 * mq;
      float s = 0;
#pragma unroll
      for (int c = 0; c < 16; c++) s += areg[c] * xb[c];
#pragma unroll
      for (int c = 0; c < 16; c++) s += areg[16 + c] * xb[20 + c];
      s += __shfl_xor(s, 1, 64); s += __shfl_xor(s, 2, 64);
      if (mq == 0) sPu[SEG(mr)] = s;
    }
    if (tid < 256) {  // dz[s4] = D[s4,:].S[:,t+1] - Egg^T[s4,:].P[:,t+1]
      const int s4 = tid >> 3, p3 = tid & 7;
      if (hn && s4 <= t) {
        const float* er = sEggT + s4 * LTR + 16 * p3;
        const float* pr = sPT + (t + 1) * PTS + 16 * p3;
        float a = 0;
#pragma unroll
        for (int kk = 0; kk < 16; kk++) a -= er[kk] * pr[kk];
        const float4 dv = *(const float4*)(sD + s4 * L36 + 4 * p3);
        const float4 sv = *(const float4*)(sS + (t + 1) * L36 + 4 * p3);  // S symmetric
        a += dot4(dv, sv);
        a += __shfl_xor(a, 1, 64); a += __shfl_xor(a, 2, 64); a += __shfl_xor(a, 4, 64);
        if (p3 == 0) sDz[s4] = a;
      }
    } else if (tid < 320) {  // wave 4: B2 = Egg_t . P[:,t]
      float a = sEggT[t * LTR + ln] * sPT[t * PTS + ln] +
                sEggT[t * LTR + ln + 64] * sPT[t * PTS + ln + 64];
      a = wsum64(a);
      if (ln == 0) sScal[SC_B2] = a;
    } else if (tid < 384) {  // wave 5: lanes<32: B1 ; lanes>=32: R12 = wU.Pm
      if (ln < 32) {
        float a = sD[t * L36 + ln] * sS[t * L36 + ln];
        a = wsum32(a);
        if (ln == 0) sScal[SC_B1] = a;
      } else {
        const int k0 = (ln - 32) * 4;
        const float4 wu4 = *(const float4*)(sWU + SEG(k0));
        const float4 pm4 = *(const float4*)(sPm + SEG(k0));
        float a = dot4(wu4, pm4);
        a = wsum32(a);
        if (ln == 32) sScal[SC_R12] = a;
      }
    } else if (tid < 448) {  // wave 6: G/Y appends (both layouts)
      const float sig = sScal[SC_SIG];
      const float rsq = rsqrtf(sig);
#pragma unroll
      for (int u = 0; u < 2; u++) {
        const int k = ln + 64 * u;
        const float wu = sWU[SEG(k)];
        const float gv = wu / sig;
        const float yv = wu * rsq;
        sGT[t * LTR + k] = gv;
        sGk[k * LKM + t] = gv;
        sYT[t * LTR + k] = yv;
        sYk[k * LKM + t] = yv;
      }
    }
    __syncthreads();
    // ---- PH4: q_next ; R11 ----
    if (hn) {
      const float* gk = sGk + mr * LKM + 8 * mq;
      const float* dzb = sDz + 8 * mq;
      float a = 0;
#pragma unroll
      for (int u = 0; u < 8; u++) {
        const int s2 = 8 * mq + u;
        a += (s2 < t) ? gk[u] * dzb[u] : 0.0f;
      }
      a += __shfl_xor(a, 1, 64); a += __shfl_xor(a, 2, 64);
      if (mq == 0)
        sQ[SEG(mr)] = sPT[(t + 1) * PTS + mr] + a + (sWU[SEG(mr)] / sScal[SC_SIG]) * sDz[t];
    }
    if (wv == 0) {  // R11 = wU . Pu
      float a = sWU[SEG(ln)] * sPu[SEG(ln)] + sWU[SEG(ln + 64)] * sPu[SEG(ln + 64)];
      a = wsum64(a);
      if (ln == 0) sScal[SC_R11] = a;
    }
    __syncthreads();
    // ---- PH5: Ainv rank-2 update (per-thread scalar finalize) ; w_next ----
    {
      const float4 sc0 = *(const float4*)(sScal);      // S2, SIG, KL, B1
      const float4 sc1 = *(const float4*)(sScal + 4);  // B2, R11, R12, R22
      const float rs = 1.0f / sc0.y;
      const float beta = sc0.w - sc1.x - sc0.x;
      const float e11 = sc1.y * rs * rs;
      const float e12 = sc1.z * rs + 1.0f;
      const float e22 = sc1.w - beta;
      const float rd = 1.0f / (e11 * e22 - e12 * e12);
      const float t11 = e22 * rd, t12 = -e12 * rd, t22 = e11 * rd;
      const float u1r = sPu[SEG(mr)] * rs, u2r = sPm[SEG(mr)];
      const float* pub = sPu + 40 * mq;
      const float* pmb = sPm + 40 * mq;
#pragma unroll
      for (int c = 0; c < 16; c++) {
        const float u1c = pub[c] * rs;
        const float u2c = pmb[c];
        areg[c] -= u1r * (t11 * u1c + t12 * u2c) + u2r * (t12 * u1c + t22 * u2c);
      }
#pragma unroll
      for (int c = 0; c < 16; c++) {
        const float u1c = pub[20 + c] * rs;
        const float u2c = pmb[20 + c];
        areg[16 + c] -= u1r * (t11 * u1c + t12 * u2c) + u2r * (t12 * u1c + t22 * u2c);
      }
    }
    if (hn) {
      const float* xb = sQ + 40 * mq;
      float s = 0;
#pragma unroll
      for (int c = 0; c < 16; c++) s += areg[c] * xb[c];
#pragma unroll
      for (int c = 0; c < 16; c++) s += areg[16 + c] * xb[20 + c];
      s += __shfl_xor(s, 1, 64); s += __shfl_xor(s, 2, 64);
      if (mq == 0) sW[SEG(mr)] = s;
    }
    __syncthreads();
  }

  // ================= fused postA =================
  float* sR1T  = uni2;         // [32][36]  (over dead sYT)
  float* sGamT = uni2 + 1152;  // [32][36]
  float* sRhsT = uni1;         // [32][132] (over dead sYk)
  float* sWrT  = uni3;         // [32][132] (over sGk -- dead after PA1)
  if (tid == 0) wsKL[b] = sScal[SC_KL];

  // ---- PA0: R1T[e][s] = D[s,:].S[e,:] - EggT[s,:].PT[e,:] ----
#pragma unroll
  for (int h = 0; h < 2; ++h) {
    const int lin = tid + 512 * h, s = lin >> 5, e = lin & 31;
    const float4* er = (const float4*)(sEggT + s * LTR);
    const float4* pr = (const float4*)(sPT + e * PTS);
    float a = 0;
#pragma unroll 8
    for (int u = 0; u < 32; ++u) a -= dot4(er[u], pr[u]);
    const float4* dr = (const float4*)(sD + s * L36);
    const float4* sr = (const float4*)(sS + e * L36);
#pragma unroll
    for (int u = 0; u < 8; ++u) a += dot4(dr[u], sr[u]);
    sR1T[e * 36 + s] = a;
  }
  __syncthreads();
  // ---- PA1: RhsT[e][k] = PT[e][k] + sum_s G[k][s] R1T[e][s] ----
  {
    const int k = tid & 127, e4 = tid >> 7;
    float4 g0, g1, g2, g3, g4, g5, g6, g7;
    {
      const float4* gk = (const float4*)(sGk + k * LKM);
      g0 = gk[0]; g1 = gk[1]; g2 = gk[2]; g3 = gk[3];
      g4 = gk[4]; g5 = gk[5]; g6 = gk[6]; g7 = gk[7];
    }
#pragma unroll
    for (int u = 0; u < 8; ++u) {
      const int e = e4 * 8 + u;
      const float4* r1 = (const float4*)(sR1T + e * 36);
      float a = sPT[e * PTS + k];
      a += dot4(g0, r1[0]) + dot4(g1, r1[1]) + dot4(g2, r1[2]) + dot4(g3, r1[3]);
      a += dot4(g4, r1[4]) + dot4(g5, r1[5]) + dot4(g6, r1[6]) + dot4(g7, r1[7]);
      sRhsT[e * PTS + k] = a;
    }
  }
  __syncthreads();
  // ---- PA2: WrT[e][k] = AinvP . rhs[:,e]  (areg matvec, 32 episodes) ----
#pragma unroll 2
  for (int e = 0; e < EE; ++e) {
    const float* xb = sRhsT + e * PTS + 32 * mq;
    float s = 0;
#pragma unroll
    for (int c = 0; c < 32; c++) s += areg[c] * xb[c];
    s += __shfl_xor(s, 1, 64); s += __shfl_xor(s, 2, 64);
    if (mq == 0) sWrT[e * PTS + mr] = s;
  }
  __syncthreads();
  // ---- PA3: GamT[e][s] = sum_k G[k][s] Wr[k][e] = GT[s,:].WrT[e,:] ----
#pragma unroll
  for (int h = 0; h < 2; ++h) {
    const int lin = tid + 512 * h, s = lin >> 5, e = lin & 31;
    const float4* gr = (const float4*)(sGT + s * LTR);
    const float4* wr = (const float4*)(sWrT + e * PTS);
    float a = 0;
#pragma unroll 8
    for (int u = 0; u < 32; ++u) a += dot4(gr[u], wr[u]);
    sGamT[e * 36 + s] = a;
  }
  __syncthreads();
  // ---- PA4: Wc -> wsWt rows 0..127 ; Vc -> rows 128..159 ; KLr ----
  {
    const int k = tid & 127, e4 = tid >> 7;
    float4 E0, E1, E2, E3, E4, E5, E6, E7;
    {
      const float4* ek = (const float4*)(sEk + k * LKM);
      E0 = ek[0]; E1 = ek[1]; E2 = ek[2]; E3 = ek[3];
      E4 = ek[4]; E5 = ek[5]; E6 = ek[6]; E7 = ek[7];
    }
#pragma unroll
    for (int u = 0; u < 8; ++u) {
      const int e = e4 * 8 + u;
      const float4* gm = (const float4*)(sGamT + e * 36);
      float a = sWrT[e * PTS + k];
      a -= dot4(E0, gm[0]) + dot4(E1, gm[1]) + dot4(E2, gm[2]) + dot4(E3, gm[3]);
      a -= dot4(E4, gm[4]) + dot4(E5, gm[5]) + dot4(E6, gm[6]) + dot4(E7, gm[7]);
      wsWt[(size_t)b * 5120 + e * 160 + k] = a;
    }
  }
  {  // Vc[e][sp] = sum_f D[f][sp] * GamT[e][f]
    const int e = tid & 31, sp = tid >> 5;  // sp in 0..15, handle sp and sp+16
    float4 gm[8];
    {
      const float4* g4 = (const float4*)(sGamT + e * 36);
#pragma unroll
      for (int u = 0; u < 8; ++u) gm[u] = g4[u];
    }
#pragma unroll
    for (int h = 0; h < 2; ++h) {
      const int sp2 = sp + 16 * h;
      float a = 0;
#pragma unroll
      for (int u = 0; u < 8; ++u) {
        const float4 g = gm[u];
        a += sD[(4 * u + 0) * L36 + sp2] * g.x + sD[(4 * u + 1) * L36 + sp2] * g.y +
             sD[(4 * u + 2) * L36 + sp2] * g.z + sD[(4 * u + 3) * L36 + sp2] * g.w;
      }
      wsWt[(size_t)b * 5120 + e * 160 + 128 + sp2] = a;
    }
  }
  {  // KLr[e] = sum_k Wr[k][e]^2
    const int e = tid >> 4, p = tid & 15;
    const float4* wr = (const float4*)(sWrT + e * PTS + 8 * p);
    const float4 w0 = wr[0], w1 = wr[1];
    float a = dot4(w0, w0) + dot4(w1, w1);
    a += __shfl_xor(a, 1, 64); a += __shfl_xor(a, 2, 64);
    a += __shfl_xor(a, 4, 64); a += __shfl_xor(a, 8, 64);
    if (p == 0) wsKLr[b * EE + e] = a;
  }
}

// ---------------- Kernel 4: postB (256 WGs) + final (block 256) ----------------
__global__ __launch_bounds__(512) void postBF_kernel(
    const float* __restrict__ wsWt, const float* __restrict__ x,
    const float* __restrict__ M0, const float* __restrict__ znoise,
    const float* __restrict__ wsKL, const float* __restrict__ wsKLr,
    const float* __restrict__ lwsP, float* __restrict__ out) {
  __shared__ __align__(16) float sWtT[32 * LWT];   // Wt^T : [e][row], stride 176
  __shared__ __align__(16) float Mch[2 * 16 * 132];
  const int tid = threadIdx.x;

  if (blockIdx.x == 256) {
    // ======== final: total divergence ========
    float* sPp = sWtT;  // reuse
    float s = 0.0f;
    if (tid < 64) s += wsKL[tid];
    for (int i = tid; i < 2048; i += 512) s += wsKLr[i];
    sPp[tid] = s;
    __syncthreads();
    for (int off = 256; off > 0; off >>= 1) {
      if (tid < off) sPp[tid] += sPp[tid + off];
      __syncthreads();
    }
    if (tid == 0) {
      const float lws = lwsP[0];
      const float sw2 = expf(2.0f * lws);
      out[(size_t)BB * EE * CC] =
          0.5f * sPp[0] / (float)(EE * BB) + (float)KK * (sw2 - 1.0f - 2.0f * lws);
    }
    return;
  }

  const int b = blockIdx.x >> 2, cq = blockIdx.x & 3;
  {
    // wsWt is [b][e][160]: direct (no transpose) load
    const int e = tid >> 4, j = tid & 15;
    const float* Wg = wsWt + (size_t)b * 5120 + e * 160;
#pragma unroll
    for (int u = 0; u < 10; ++u) sWtT[e * LWT + j + 16 * u] = Wg[j + 16 * u];
  }
  const int srow = tid >> 5, sc4 = tid & 31;  // stage: 16 rows x 32 float4 (128 cols)
  const int e = tid & 31, cs = tid >> 5;      // compute: episode e, col-octet cs
  const float* xb = x + (size_t)b * EE * CC;
  const int cbase = cq * 128;
  float4 st = *(const float4*)(M0 + srow * CC + cbase + 4 * sc4);  // ch2=0 rows are all M0
  float acc[8];
#pragma unroll
  for (int u = 0; u < 8; u++) acc[u] = 0.0f;
  int buf = 0;
#pragma unroll 1
  for (int ch2 = 0; ch2 < 10; ++ch2) {
    *(float4*)(Mch + buf * 2112 + srow * 132 + 4 * sc4) = st;
    __syncthreads();
    if (ch2 + 1 < 10) {
      const int row = (ch2 + 1) * 16 + srow;
      st = (row < 128) ? *(const float4*)(M0 + row * CC + cbase + 4 * sc4)
                       : *(const float4*)(xb + (row - 128) * CC + cbase + 4 * sc4);
    }
    const float4* wt4 = (const float4*)(sWtT + e * LWT + ch2 * 16);
    const float4 wa = wt4[0], wb = wt4[1], wc = wt4[2], wd = wt4[3];
    const float wv16[16] = {wa.x, wa.y, wa.z, wa.w, wb.x, wb.y, wb.z, wb.w,
                            wc.x, wc.y, wc.z, wc.w, wd.x, wd.y, wd.z, wd.w};
#pragma unroll
    for (int kk = 0; kk < 16; ++kk) {
      const float* mrp = Mch + buf * 2112 + kk * 132 + cs * 8;
      const float4 m0 = *(const float4*)(mrp);
      const float4 m1 = *(const float4*)(mrp + 4);
      const float wk = wv16[kk];
      acc[0] += wk * m0.x; acc[1] += wk * m0.y; acc[2] += wk * m0.z; acc[3] += wk * m0.w;
      acc[4] += wk * m1.x; acc[5] += wk * m1.y; acc[6] += wk * m1.z; acc[7] += wk * m1.w;
    }
    buf ^= 1;
  }
  {
    const size_t ob = ((size_t)b * EE + e) * CC + cbase + cs * 8;
    const size_t nb = ((size_t)e * BB + b) * CC + cbase + cs * 8;
#pragma unroll
    for (int u = 0; u < 2; u++) {
      const float4 nz = *(const float4*)(znoise + nb + 4 * u);
      float4 o;
      o.x = acc[4 * u] + nz.x;     o.y = acc[4 * u + 1] + nz.y;
      o.z = acc[4 * u + 2] + nz.z; o.w = acc[4 * u + 3] + nz.w;
      *(float4*)(out + ob + 4 * u) = o;
    }
  }
}

extern "C" void kernel_launch(void* const* d_in, const int* in_sizes, int n_in,
                              void* d_out, int out_size, void* d_ws, size_t ws_size,
                              hipStream_t stream) {
  (void)in_sizes; (void)n_in; (void)out_size; (void)ws_size;
  const float* x = (const float*)d_in[0];        // [B,E,C]
  const float* M0 = (const float*)d_in[1];       // [K,C]
  const float* scaleP = (const float*)d_in[2];   // scalar
  const float* lwsP = (const float*)d_in[3];     // scalar
  const float* znoise = (const float*)d_in[4];   // [E,B,C]
  float* out = (float*)d_out;

  float* ws = (float*)d_ws;
  float* wsP = ws;                        // 262144
  float* wsSp = wsP + 262144;             // 262144 (64 x 4 partials x 1024)
  float* wsA0 = wsSp + 262144;            // 16384
  float* wsAinv0 = wsA0 + 16384;          // 16384
  float* wsKL = wsAinv0 + 16384;          // 64
  float* wsKLr = wsKL + 64;               // 2048
  float* wsWt = wsKLr + 2048;             // 327680 (64 x 32 x 160, [b][e][row])

  a0_kernel<<<512, 256, 0, stream>>>(M0, wsA0);
  psinv_kernel<<<257, 1024, 0, stream>>>(x, M0, wsP, wsSp, wsA0, wsAinv0);
  scan_kernel<<<BB, 512, 0, stream>>>(wsP, wsSp, scaleP, wsAinv0,
                                      wsKL, wsKLr, wsWt);
  postBF_kernel<<<257, 512, 0, stream>>>(wsWt, x, M0, znoise, wsKL, wsKLr, lwsP, out);
}